// Round 10
// baseline (1089.521 us; speedup 1.0000x reference)
//
#include <hip/hip_runtime.h>
#include <math.h>

// Problem dims
#define BD 32
#define CD 768
#define HWD 4096
#define DD 768
#define HRD 128
#define KD 64

// Output offsets (floats), in reference return order
#define O_SPATIAL 0ull
#define O_CG      100663296ull   // context_global [B,D]
#define O_LW      100687872ull   // level_weights [B,L]
#define O_LMIX    100687968ull   // level_mix [B,L,2]
#define O_ENT     100688160ull   // attn_entropy [B]
#define O_TOKEN   100688192ull   // token [B,D]
#define O_APL     100712768ull   // attn_per_level [L,B,2,K]

// Workspace offsets (floats)
#define W_INV      0            // 384 inv-norms [s*192 + l*64 + k]
#define W_POOLED   384          // 32*768

// native vector type for nontemporal builtins (float4 is a class -> rejected)
typedef float f32x4 __attribute__((ext_vector_type(4)));

__device__ __forceinline__ float dot4(float4 a, float4 b) {
    return a.x * b.x + a.y * b.y + a.z * b.z + a.w * b.w;
}
__device__ __forceinline__ float gelu_f(float a) {
    return 0.5f * a * (1.0f + erff(a * 0.70710678118f));
}

// ---------------- K1: mean pool (wave-per-row) + bank norms ----------------
// blocks [0,6144): 4 pooled rows each (wave per row), 16-deep nontemporal loads
// blocks [6144,6240): 4 bank-norm rows each (wave per row)
__global__ __launch_bounds__(256) void k_pool(const float* __restrict__ f,
                                              const float* __restrict__ fastb,
                                              const float* __restrict__ slowb,
                                              float* __restrict__ ws) {
    int t = threadIdx.x;
    int wv = t >> 6, lane = t & 63;
    int bx = blockIdx.x;
    if (bx < 6144) {
        int row = bx * 4 + wv;   // b*C + c
        const f32x4* src = reinterpret_cast<const f32x4*>(f) + (size_t)row * (HWD / 4);
        f32x4 a[16];
#pragma unroll
        for (int i = 0; i < 16; i++)
            a[i] = __builtin_nontemporal_load(&src[lane + 64 * i]);
        f32x4 s4 = (f32x4)(0.f);
#pragma unroll
        for (int i = 0; i < 16; i++) s4 += a[i];
        float s = (s4.x + s4.y) + (s4.z + s4.w);
#pragma unroll
        for (int o = 32; o > 0; o >>= 1) s += __shfl_down(s, o);
        if (lane == 0) ws[W_POOLED + row] = s * (1.0f / HWD);
    } else {
        int r = (bx - 6144) * 4 + wv;   // 384 bank rows
        const float* row = (r < 192 ? fastb : slowb) + (size_t)(r % 192) * DD;
        const float4* row4 = reinterpret_cast<const float4*>(row);
        float4 v0 = row4[lane], v1 = row4[lane + 64], v2 = row4[lane + 128];
        float ss = dot4(v0, v0) + dot4(v1, v1) + dot4(v2, v2);
#pragma unroll
        for (int o = 32; o > 0; o >>= 1) ss += __shfl_down(ss, o);
        if (lane == 0) ws[W_INV + r] = 1.0f / fmaxf(sqrtf(ss), 1e-12f);
    }
}

// ---------------- K2: per-batch fused middle (one block per b) ----------------
// q -> token -> routing MLP -> gates -> logits -> softmax/entropy -> contexts
// -> context_global + all small outputs. No atomics, no cross-block deps.
__global__ __launch_bounds__(256) void k_mid(const float* __restrict__ wq,
                                             const float* __restrict__ rw1,
                                             const float* __restrict__ rb1,
                                             const float* __restrict__ rw2,
                                             const float* __restrict__ rb2,
                                             const float* __restrict__ mgw1,
                                             const float* __restrict__ mgb1,
                                             const float* __restrict__ mgw2,
                                             const float* __restrict__ mgb2,
                                             const float* __restrict__ fastb,
                                             const float* __restrict__ slowb,
                                             const float* __restrict__ fastc,
                                             const float* __restrict__ slowc,
                                             float* __restrict__ ws,
                                             float* __restrict__ out) {
    int b = blockIdx.x, t = threadIdx.x;
    int wv = t >> 6, lane = t & 63;
    __shared__ float sp[DD];          // pooled
    __shared__ float st[DD];          // token
    __shared__ float red[256];        // generic reduce / hpart buffer
    __shared__ float slog[384];       // retrieval logits [s*192+l*64+k]
    __shared__ float sattnw[6 * KD];  // attn * invnorm, [ (s*3+l)*64 + k ]
    __shared__ float r23[2][3];
    __shared__ float gred[4];
    __shared__ float slw[3], smix[3], sent[6];

    // ---- load pooled[b] ----
    sp[t]       = ws[W_POOLED + (size_t)b * DD + t];
    sp[t + 256] = ws[W_POOLED + (size_t)b * DD + t + 256];
    sp[t + 512] = ws[W_POOLED + (size_t)b * DD + t + 512];
    __syncthreads();

    // ---- q = pooled @ wq^T : rows t, t+256, t+512 per thread ----
    const float4* sp4 = reinterpret_cast<const float4*>(sp);
    const float4* r0 = reinterpret_cast<const float4*>(wq + (size_t)t * DD);
    const float4* r1 = reinterpret_cast<const float4*>(wq + (size_t)(t + 256) * DD);
    const float4* r2 = reinterpret_cast<const float4*>(wq + (size_t)(t + 512) * DD);
    float q0 = 0.f, q1 = 0.f, q2 = 0.f;
#pragma unroll 8
    for (int c = 0; c < DD / 4; c++) {
        float4 p = sp4[c];
        q0 += dot4(r0[c], p);
        q1 += dot4(r1[c], p);
        q2 += dot4(r2[c], p);
    }
    float ss = q0 * q0 + q1 * q1 + q2 * q2;
#pragma unroll
    for (int o = 32; o > 0; o >>= 1) ss += __shfl_down(ss, o);
    if (lane == 0) red[wv] = ss;
    __syncthreads();
    float inv_t = 1.0f / fmaxf(sqrtf(red[0] + red[1] + red[2] + red[3]), 1e-12f);
    float tk0 = q0 * inv_t, tk1 = q1 * inv_t, tk2 = q2 * inv_t;
    st[t] = tk0; st[t + 256] = tk1; st[t + 512] = tk2;
    out[O_TOKEN + (size_t)b * DD + t]       = tk0;
    out[O_TOKEN + (size_t)b * DD + t + 256] = tk1;
    out[O_TOKEN + (size_t)b * DD + t + 512] = tk2;

    // ---- routing MLP (uses pooled) ----
    {
        int o = t & 127, ci = t >> 7;
        float acc = ci ? 0.f : rb1[o];
        const float* col = rw1 + o;
        int c0 = ci * 384;
#pragma unroll 8
        for (int c = c0; c < c0 + 384; c++) acc += sp[c] * col[c * HRD];
        __syncthreads();   // red (inv reduce) consumed by all; st writes done
        red[t] = acc;
        __syncthreads();
        float pr0 = 0.f, pr1 = 0.f, pr2 = 0.f;
        if (t < 128) {
            float a = red[t] + red[t + 128];
            float h = gelu_f(a);
            pr0 = h * rw2[t * 3 + 0];
            pr1 = h * rw2[t * 3 + 1];
            pr2 = h * rw2[t * 3 + 2];
        }
#pragma unroll
        for (int oo = 32; oo > 0; oo >>= 1) {
            pr0 += __shfl_down(pr0, oo);
            pr1 += __shfl_down(pr1, oo);
            pr2 += __shfl_down(pr2, oo);
        }
        if (t < 128 && (t & 63) == 0) {
            r23[t >> 6][0] = pr0; r23[t >> 6][1] = pr1; r23[t >> 6][2] = pr2;
        }
        __syncthreads();
        if (t == 0) {
            float lg0 = r23[0][0] + r23[1][0] + rb2[0];
            float lg1 = r23[0][1] + r23[1][1] + rb2[1];
            float lg2 = r23[0][2] + r23[1][2] + rb2[2];
            float m = fmaxf(lg0, fmaxf(lg1, lg2));
            float e0 = expf(lg0 - m), e1 = expf(lg1 - m), e2 = expf(lg2 - m);
            float s = e0 + e1 + e2;
            slw[0] = e0 / s; slw[1] = e1 / s; slw[2] = e2 / s;
            out[O_LW + b * 3 + 0] = e0 / s;
            out[O_LW + b * 3 + 1] = e1 / s;
            out[O_LW + b * 3 + 2] = e2 / s;
        }
    }

    // ---- mix gates (uses token) ----
    for (int l = 0; l < 3; l++) {
        float part = 0.f;
        {
            int hh = t;
            float acc = mgb1[l * 384 + hh];
            const float* wc = mgw1 + (size_t)l * DD * 384 + hh;
#pragma unroll 8
            for (int d = 0; d < DD; d++) acc += st[d] * wc[(size_t)d * 384];
            part = gelu_f(acc) * mgw2[l * 384 + hh];
        }
        if (t < 128) {
            int hh = 256 + t;
            float acc = mgb1[l * 384 + hh];
            const float* wc = mgw1 + (size_t)l * DD * 384 + hh;
#pragma unroll 8
            for (int d = 0; d < DD; d++) acc += st[d] * wc[(size_t)d * 384];
            part += gelu_f(acc) * mgw2[l * 384 + hh];
        }
#pragma unroll
        for (int oo = 32; oo > 0; oo >>= 1) part += __shfl_down(part, oo);
        __syncthreads();               // protect gred reuse across levels
        if (lane == 0) gred[wv] = part;
        __syncthreads();
        if (t == 0)
            smix[l] = 1.0f / (1.0f + expf(-(gred[0] + gred[1] + gred[2] + gred[3] + mgb2[l])));
    }

    // ---- retrieval logits: rows r = s*192 + l*64 + k ----
    {
        const float4* st4 = reinterpret_cast<const float4*>(st);
        {
            int r = t;
            const float4* br = reinterpret_cast<const float4*>(
                (r < 192 ? fastb : slowb) + (size_t)(r % 192) * DD);
            float acc = 0.f;
#pragma unroll 8
            for (int c = 0; c < DD / 4; c++) acc += dot4(br[c], st4[c]);
            slog[r] = acc * ws[W_INV + r] * 0.03608439182435161f;
        }
        if (t < 128) {
            int r = 256 + t;
            const float4* br = reinterpret_cast<const float4*>(
                slowb + (size_t)(r % 192) * DD);
            float acc = 0.f;
#pragma unroll 8
            for (int c = 0; c < DD / 4; c++) acc += dot4(br[c], st4[c]);
            slog[r] = acc * ws[W_INV + r] * 0.03608439182435161f;
        }
    }
    __syncthreads();

    // ---- softmax + entropy per (s,l), wave 0 only ----
    if (t < 64) {
        int k = t;
        for (int ls = 0; ls < 6; ls++) {      // ls = s*3 + l
            int s_ = ls / 3, l = ls % 3;
            const float* cnts = (s_ ? slowc : fastc) + l * KD;
            bool ready = cnts[k] > 1e-6f;
            float x = ready ? slog[s_ * 192 + l * 64 + k] : -__builtin_inff();
            float m = x;
#pragma unroll
            for (int o = 32; o > 0; o >>= 1) m = fmaxf(m, __shfl_xor(m, o));
            float e = ready ? expf(x - m) : 0.f;
            float sum = e;
#pragma unroll
            for (int o = 32; o > 0; o >>= 1) sum += __shfl_xor(sum, o);
            float attn = e / sum;
            out[O_APL + ((size_t)(l * BD + b) * 2 + s_) * KD + k] = attn;
            sattnw[ls * KD + k] = attn * ws[W_INV + s_ * 192 + l * 64 + k];
            float p = fmaxf(attn, 1e-8f);
            float term = ready ? p * logf(p) : 0.f;
#pragma unroll
            for (int o = 32; o > 0; o >>= 1) term += __shfl_xor(term, o);
            if (k == 0) sent[ls] = -term;
        }
    }
    __syncthreads();

    // ---- contexts + combine -> context_global ----
    float cg0 = 0.f, cg1 = 0.f, cg2 = 0.f;
    for (int ls = 0; ls < 6; ls++) {
        int s_ = ls / 3, l = ls % 3;
        const float* bank = (s_ ? slowb : fastb) + (size_t)l * KD * DD;
        float c0 = 0.f, c1 = 0.f, c2 = 0.f;
#pragma unroll 4
        for (int k2 = 0; k2 < KD; k2++) {
            float wgt = sattnw[ls * KD + k2];
            const float* row = bank + (size_t)k2 * DD;
            c0 += wgt * row[t];
            c1 += wgt * row[t + 256];
            c2 += wgt * row[t + 512];
        }
        float coef = slw[l] * (s_ ? (1.0f - smix[l]) : smix[l]);
        cg0 += coef * c0; cg1 += coef * c1; cg2 += coef * c2;
    }
    out[O_CG + (size_t)b * DD + t]       = cg0;
    out[O_CG + (size_t)b * DD + t + 256] = cg1;
    out[O_CG + (size_t)b * DD + t + 512] = cg2;
    if (t == 0) {
        float ae = 0.f;
#pragma unroll
        for (int l = 0; l < 3; l++)
            ae += slw[l] * (sent[l] + sent[3 + l]) * 0.5f;
        out[O_ENT + b] = ae;
#pragma unroll
        for (int l = 0; l < 3; l++) {
            out[O_LMIX + ((size_t)b * 3 + l) * 2 + 0] = smix[l];
            out[O_LMIX + ((size_t)b * 3 + l) * 2 + 1] = 1.0f - smix[l];
        }
    }
}

// ---------------- K3: spatial broadcast (nontemporal stores) ----------------
__global__ __launch_bounds__(256) void k_bcast(float* __restrict__ out) {
    int b = blockIdx.y, j = blockIdx.x, t = threadIdx.x;
    __shared__ float cg[4];
    if (t < 4) cg[t] = out[O_CG + (size_t)b * DD + j * 4 + t];
    __syncthreads();
#pragma unroll
    for (int ch = 0; ch < 4; ch++) {
        float v = cg[ch];
        f32x4 v4 = (f32x4)(v);
        f32x4* dst = reinterpret_cast<f32x4*>(out + O_SPATIAL +
                        ((size_t)(b * CD) + j * 4 + ch) * HWD);
#pragma unroll
        for (int i = 0; i < 4; i++)
            __builtin_nontemporal_store(v4, &dst[t + 256 * i]);
    }
}

extern "C" void kernel_launch(void* const* d_in, const int* in_sizes, int n_in,
                              void* d_out, int out_size, void* d_ws, size_t ws_size,
                              hipStream_t stream) {
    const float* features = (const float*)d_in[0];
    const float* w_query  = (const float*)d_in[1];
    const float* rw1      = (const float*)d_in[2];
    const float* rb1      = (const float*)d_in[3];
    const float* rw2      = (const float*)d_in[4];
    const float* rb2      = (const float*)d_in[5];
    const float* mg_w1    = (const float*)d_in[6];
    const float* mg_b1    = (const float*)d_in[7];
    const float* mg_w2    = (const float*)d_in[8];
    const float* mg_b2    = (const float*)d_in[9];
    const float* fastb    = (const float*)d_in[10];
    const float* slowb    = (const float*)d_in[11];
    const float* fastc    = (const float*)d_in[12];
    const float* slowc    = (const float*)d_in[13];
    float* out = (float*)d_out;
    float* ws  = (float*)d_ws;

    hipLaunchKernelGGL(k_pool, dim3(6240), dim3(256), 0, stream,
                       features, fastb, slowb, ws);
    hipLaunchKernelGGL(k_mid, dim3(BD), dim3(256), 0, stream,
                       w_query, rw1, rb1, rw2, rb2,
                       mg_w1, mg_b1, mg_w2, mg_b2,
                       fastb, slowb, fastc, slowc, ws, out);
    hipLaunchKernelGGL(k_bcast, dim3(192, BD), dim3(256), 0, stream, out);
}

// Round 11
// 731.067 us; speedup vs baseline: 1.4903x; 1.4903x over previous
//
#include <hip/hip_runtime.h>
#include <math.h>

// Problem dims
#define BD 32
#define CD 768
#define HWD 4096
#define DD 768
#define HRD 128
#define LD 3
#define KD 64

// Output offsets (floats), in reference return order
#define O_SPATIAL 0ull
#define O_CG      100663296ull   // context_global [B,D]
#define O_LW      100687872ull   // level_weights [B,L]
#define O_LMIX    100687968ull   // level_mix [B,L,2]
#define O_ENT     100688160ull   // attn_entropy [B]
#define O_TOKEN   100688192ull   // token [B,D]
#define O_APL     100712768ull   // attn_per_level [L,B,2,K]

// Workspace offsets (floats)
#define W_POOLED   0            // 32*768
#define W_Q        24576        // 32*768 (unnormalized token)
#define W_QSS      49152        // 32 (sum of squares per b, atomic)
#define W_INV      49184        // 384 inv-norms [s*192 + l*64 + k]
#define W_MIXL     49568        // 96 mix logits [l*32 + b] (atomic)
#define W_CTX      49664        // 2*3*32*768 contexts [((s*3+l)*32+b)*768+d]
#define W_ENT      197120       // 2*3*32 entropies [(s*3+l)*32+b]

// native vector type for nontemporal builtins (float4 is a class -> rejected)
typedef float f32x4 __attribute__((ext_vector_type(4)));

__device__ __forceinline__ float dot4(float4 a, float4 b) {
    return a.x * b.x + a.y * b.y + a.z * b.z + a.w * b.w;
}
__device__ __forceinline__ float gelu_f(float a) {
    return 0.5f * a * (1.0f + erff(a * 0.70710678118f));
}

// ---------------- K1: mean pool (wave-per-row) + bank norms + zeroing ----------------
__global__ __launch_bounds__(256) void k_pool(const float* __restrict__ f,
                                              const float* __restrict__ fastb,
                                              const float* __restrict__ slowb,
                                              float* __restrict__ ws) {
    int t = threadIdx.x;
    int wv = t >> 6, lane = t & 63;
    int bx = blockIdx.x;
    if (bx < 6144) {
        int row = bx * 4 + wv;   // b*C + c
        const f32x4* src = reinterpret_cast<const f32x4*>(f) + (size_t)row * (HWD / 4);
        f32x4 a[16];
#pragma unroll
        for (int i = 0; i < 16; i++)
            a[i] = __builtin_nontemporal_load(&src[lane + 64 * i]);
        f32x4 s4 = (f32x4)(0.f);
#pragma unroll
        for (int i = 0; i < 16; i++) s4 += a[i];
        float s = (s4.x + s4.y) + (s4.z + s4.w);
#pragma unroll
        for (int o = 32; o > 0; o >>= 1) s += __shfl_down(s, o);
        if (lane == 0) ws[W_POOLED + row] = s * (1.0f / HWD);
    } else if (bx < 6240) {
        int r = (bx - 6144) * 4 + wv;   // 384 bank rows
        const float* row = (r < 192 ? fastb : slowb) + (size_t)(r % 192) * DD;
        const float4* row4 = reinterpret_cast<const float4*>(row);
        float4 v0 = row4[lane], v1 = row4[lane + 64], v2 = row4[lane + 128];
        float ss = dot4(v0, v0) + dot4(v1, v1) + dot4(v2, v2);
#pragma unroll
        for (int o = 32; o > 0; o >>= 1) ss += __shfl_down(ss, o);
        if (lane == 0) ws[W_INV + r] = 1.0f / fmaxf(sqrtf(ss), 1e-12f);
    } else {
        if (t < 32) ws[W_QSS + t] = 0.f;
        if (t < 96) ws[W_MIXL + t] = 0.f;
    }
}

// ---------------- K2: q = pooled @ w_query^T (+sumsq) and routing MLP ----------------
__global__ __launch_bounds__(256) void k_qh(const float* __restrict__ wq,
                                            const float* __restrict__ rw1,
                                            const float* __restrict__ rb1,
                                            const float* __restrict__ rw2,
                                            const float* __restrict__ rb2,
                                            float* __restrict__ ws,
                                            float* __restrict__ out) {
    int b = blockIdx.y, j = blockIdx.x, t = threadIdx.x;
    if (j < 24) {
        // 32 rows of q per block; 4 waves x 8 rows, 8 independent chains per wave
        int w = t >> 6, lane = t & 63;
        const float4* p4 = reinterpret_cast<const float4*>(ws + W_POOLED + (size_t)b * DD);
        float4 p0 = p4[lane], p1 = p4[lane + 64], p2 = p4[lane + 128];
        float acc[8];
        int d0 = j * 32 + w * 8;
#pragma unroll
        for (int rr = 0; rr < 8; rr++) {
            const float4* row = reinterpret_cast<const float4*>(wq + (size_t)(d0 + rr) * DD);
            float4 a = row[lane], c = row[lane + 64], e = row[lane + 128];
            acc[rr] = dot4(a, p0) + dot4(c, p1) + dot4(e, p2);
        }
        __shared__ float qbuf[32];
#pragma unroll
        for (int rr = 0; rr < 8; rr++) {
            float v = acc[rr];
#pragma unroll
            for (int o = 32; o > 0; o >>= 1) v += __shfl_down(v, o);
            if (lane == 0) qbuf[w * 8 + rr] = v;
        }
        __syncthreads();
        if (t < 32) {
            float v = qbuf[t];
            ws[W_Q + (size_t)b * DD + j * 32 + t] = v;
            float ss = v * v;
#pragma unroll
            for (int o = 16; o > 0; o >>= 1) ss += __shfl_down(ss, o);
            if (t == 0) atomicAdd(&ws[W_QSS + b], ss);
        }
    } else {
        // routing MLP: h = gelu(pooled @ rw1 + rb1); lw = softmax(h @ rw2 + rb2)
        __shared__ float pooled[DD];
        __shared__ float hpart[256];
        __shared__ float r2[2][3];
        for (int i = t; i < DD; i += 256) pooled[i] = ws[W_POOLED + (size_t)b * DD + i];
        __syncthreads();
        int o = t & 127, ci = t >> 7;
        float acc = ci ? 0.f : rb1[o];
        const float* col = rw1 + o;
        int c0 = ci * 384;
#pragma unroll 8
        for (int c = c0; c < c0 + 384; c++) acc += pooled[c] * col[c * HRD];
        hpart[t] = acc;
        __syncthreads();
        float pr0 = 0.f, pr1 = 0.f, pr2 = 0.f;
        if (t < 128) {
            float a = hpart[t] + hpart[t + 128];
            float h = gelu_f(a);
            pr0 = h * rw2[t * 3 + 0];
            pr1 = h * rw2[t * 3 + 1];
            pr2 = h * rw2[t * 3 + 2];
        }
#pragma unroll
        for (int oo = 32; oo > 0; oo >>= 1) {
            pr0 += __shfl_down(pr0, oo);
            pr1 += __shfl_down(pr1, oo);
            pr2 += __shfl_down(pr2, oo);
        }
        if (t < 128 && (t & 63) == 0) {
            r2[t >> 6][0] = pr0; r2[t >> 6][1] = pr1; r2[t >> 6][2] = pr2;
        }
        __syncthreads();
        if (t == 0) {
            float lg0 = r2[0][0] + r2[1][0] + rb2[0];
            float lg1 = r2[0][1] + r2[1][1] + rb2[1];
            float lg2 = r2[0][2] + r2[1][2] + rb2[2];
            float m = fmaxf(lg0, fmaxf(lg1, lg2));
            float e0 = expf(lg0 - m), e1 = expf(lg1 - m), e2 = expf(lg2 - m);
            float s = e0 + e1 + e2;
            out[O_LW + b * 3 + 0] = e0 / s;
            out[O_LW + b * 3 + 1] = e1 / s;
            out[O_LW + b * 3 + 2] = e2 / s;
        }
    }
}

// ---------------- K3: retrieval (j<6) + mix gates (j>=6) ----------------
__global__ __launch_bounds__(256) void k_rg(const float* __restrict__ fastb,
                                            const float* __restrict__ slowb,
                                            const float* __restrict__ fastc,
                                            const float* __restrict__ slowc,
                                            const float* __restrict__ mgw1,
                                            const float* __restrict__ mgb1,
                                            const float* __restrict__ mgw2,
                                            float* __restrict__ ws,
                                            float* __restrict__ out) {
    int b = blockIdx.y, j = blockIdx.x, t = threadIdx.x;
    float inv_t = 1.0f / fmaxf(sqrtf(ws[W_QSS + b]), 1e-12f);
    const float4* q4 = reinterpret_cast<const float4*>(ws + W_Q + (size_t)b * DD);

    if (j < 6) {
        int l = j >> 1, s = j & 1;
        int w = t >> 6, lane = t & 63;
        float4 t0 = q4[lane], t1 = q4[lane + 64], t2 = q4[lane + 128];
        t0.x *= inv_t; t0.y *= inv_t; t0.z *= inv_t; t0.w *= inv_t;
        t1.x *= inv_t; t1.y *= inv_t; t1.z *= inv_t; t1.w *= inv_t;
        t2.x *= inv_t; t2.y *= inv_t; t2.z *= inv_t; t2.w *= inv_t;
        if (j == 0 && t < 192) {
            float4 v = q4[t];
            v.x *= inv_t; v.y *= inv_t; v.z *= inv_t; v.w *= inv_t;
            reinterpret_cast<float4*>(out + O_TOKEN + (size_t)b * DD)[t] = v;
        }
        __shared__ float sl_logit[KD];
        __shared__ float sl_w[KD];
        const float* bank = (s ? slowb : fastb) + (size_t)l * KD * DD;
        const float* cnts = (s ? slowc : fastc) + l * KD;
#pragma unroll 4
        for (int rr = 0; rr < 16; rr++) {
            int k = w * 16 + rr;
            const float4* row = reinterpret_cast<const float4*>(bank + (size_t)k * DD);
            float4 a = row[lane], c = row[lane + 64], e = row[lane + 128];
            float acc = dot4(a, t0) + dot4(c, t1) + dot4(e, t2);
#pragma unroll
            for (int o = 32; o > 0; o >>= 1) acc += __shfl_down(acc, o);
            if (lane == 0)
                sl_logit[k] = acc * ws[W_INV + s * 192 + l * 64 + k] * 0.03608439182435161f;
        }
        __syncthreads();
        if (t < 64) {
            int k = t;
            bool ready = cnts[k] > 1e-6f;
            float x = ready ? sl_logit[k] : -__builtin_inff();
            float m = x;
#pragma unroll
            for (int o = 32; o > 0; o >>= 1) m = fmaxf(m, __shfl_xor(m, o));
            float e = ready ? expf(x - m) : 0.f;
            float sum = e;
#pragma unroll
            for (int o = 32; o > 0; o >>= 1) sum += __shfl_xor(sum, o);
            float attn = e / sum;
            out[O_APL + ((size_t)(l * BD + b) * 2 + s) * KD + k] = attn;
            sl_w[k] = attn * ws[W_INV + s * 192 + l * 64 + k];
            float p = fmaxf(attn, 1e-8f);
            float term = ready ? p * logf(p) : 0.f;
#pragma unroll
            for (int o = 32; o > 0; o >>= 1) term += __shfl_xor(term, o);
            if (k == 0) ws[W_ENT + (s * 3 + l) * BD + b] = -term;
        }
        __syncthreads();
        // context = sum_k (attn_k * invnorm_k) * bank[k, :]
        float acc0 = 0.f, acc1 = 0.f, acc2 = 0.f;
#pragma unroll 8
        for (int k = 0; k < KD; k++) {
            float wgt = sl_w[k];
            const float* row = bank + (size_t)k * DD;
            acc0 += wgt * row[t];
            acc1 += wgt * row[t + 256];
            acc2 += wgt * row[t + 512];
        }
        size_t base = W_CTX + ((size_t)(s * 3 + l) * BD + b) * DD;
        ws[base + t] = acc0;
        ws[base + t + 256] = acc1;
        ws[base + t + 512] = acc2;
    } else {
        // mix gates
        int jj = j - 6, l = jj >> 1, half = jj & 1;
        __shared__ float token[DD];
        __shared__ float r4[4];
        if (t < 192) {
            float4 v = q4[t];
            v.x *= inv_t; v.y *= inv_t; v.z *= inv_t; v.w *= inv_t;
            reinterpret_cast<float4*>(token)[t] = v;
        }
        __syncthreads();
        float part = 0.f;
        if (t < 192) {
            int hh = half * 192 + t;
            float acc = mgb1[l * 384 + hh];
            const float* wcol = mgw1 + (size_t)l * DD * 384 + hh;
#pragma unroll 8
            for (int d = 0; d < DD; d++) acc += token[d] * wcol[(size_t)d * 384];
            part = gelu_f(acc) * mgw2[l * 384 + hh];
        }
#pragma unroll
        for (int o = 32; o > 0; o >>= 1) part += __shfl_down(part, o);
        if ((t & 63) == 0) r4[t >> 6] = part;
        __syncthreads();
        if (t == 0) atomicAdd(&ws[W_MIXL + l * BD + b], r4[0] + r4[1] + r4[2] + r4[3]);
    }
}

// ---------------- K4: combine + spatial broadcast (nontemporal stores) ----------------
__global__ __launch_bounds__(256) void k_comb(const float* __restrict__ mgb2,
                                              float* __restrict__ ws,
                                              float* __restrict__ out) {
    int b = blockIdx.y, j = blockIdx.x, t = threadIdx.x;
    float wf[3], wsl[3], mixv[3], lwv[3];
#pragma unroll
    for (int l = 0; l < 3; l++) {
        lwv[l] = out[O_LW + b * 3 + l];
        float ml = ws[W_MIXL + l * BD + b] + mgb2[l];
        mixv[l] = 1.0f / (1.0f + expf(-ml));
        wf[l] = lwv[l] * mixv[l];
        wsl[l] = lwv[l] * (1.0f - mixv[l]);
    }
    __shared__ float cg[4];
    if (t < 4) {
        int c = j * 4 + t;
        float acc = 0.f;
#pragma unroll
        for (int l = 0; l < 3; l++) {
            acc += wf[l] * ws[W_CTX + ((size_t)(0 * 3 + l) * BD + b) * DD + c]
                 + wsl[l] * ws[W_CTX + ((size_t)(1 * 3 + l) * BD + b) * DD + c];
        }
        cg[t] = acc;
        out[O_CG + (size_t)b * DD + c] = acc;
    }
    if (j == 0 && t == 64) {
        float ae = 0.f;
#pragma unroll
        for (int l = 0; l < 3; l++)
            ae += lwv[l] * (ws[W_ENT + (0 * 3 + l) * BD + b] + ws[W_ENT + (1 * 3 + l) * BD + b]) * 0.5f;
        out[O_ENT + b] = ae;
    }
    if (j == 0 && t == 128) {
#pragma unroll
        for (int l = 0; l < 3; l++) {
            out[O_LMIX + ((size_t)b * 3 + l) * 2 + 0] = mixv[l];
            out[O_LMIX + ((size_t)b * 3 + l) * 2 + 1] = 1.0f - mixv[l];
        }
    }
    __syncthreads();
#pragma unroll
    for (int ch = 0; ch < 4; ch++) {
        float v = cg[ch];
        f32x4 v4 = (f32x4)(v);
        f32x4* dst = reinterpret_cast<f32x4*>(out + O_SPATIAL +
                        ((size_t)(b * CD) + j * 4 + ch) * HWD);
#pragma unroll
        for (int i = 0; i < 4; i++)
            __builtin_nontemporal_store(v4, &dst[t + 256 * i]);
    }
}

extern "C" void kernel_launch(void* const* d_in, const int* in_sizes, int n_in,
                              void* d_out, int out_size, void* d_ws, size_t ws_size,
                              hipStream_t stream) {
    const float* features = (const float*)d_in[0];
    const float* w_query  = (const float*)d_in[1];
    const float* rw1      = (const float*)d_in[2];
    const float* rb1      = (const float*)d_in[3];
    const float* rw2      = (const float*)d_in[4];
    const float* rb2      = (const float*)d_in[5];
    const float* mg_w1    = (const float*)d_in[6];
    const float* mg_b1    = (const float*)d_in[7];
    const float* mg_w2    = (const float*)d_in[8];
    const float* mg_b2    = (const float*)d_in[9];
    const float* fastb    = (const float*)d_in[10];
    const float* slowb    = (const float*)d_in[11];
    const float* fastc    = (const float*)d_in[12];
    const float* slowc    = (const float*)d_in[13];
    float* out = (float*)d_out;
    float* ws  = (float*)d_ws;

    hipLaunchKernelGGL(k_pool, dim3(6241), dim3(256), 0, stream,
                       features, fastb, slowb, ws);
    hipLaunchKernelGGL(k_qh, dim3(25, BD), dim3(256), 0, stream,
                       w_query, rw1, rb1, rw2, rb2, ws, out);
    hipLaunchKernelGGL(k_rg, dim3(12, BD), dim3(256), 0, stream,
                       fastb, slowb, fastc, slowc, mg_w1, mg_b1, mg_w2, ws, out);
    hipLaunchKernelGGL(k_comb, dim3(192, BD), dim3(256), 0, stream, mg_b2, ws, out);
}